// Round 1
// baseline (53.980 us; speedup 1.0000x reference)
//
#include <hip/hip_runtime.h>

#define ALPHA 0.5f
#define BETA 0.5f
#define SMOOTH 1e-6f

constexpr int kB = 32, kC = 4, kH = 512, kW = 512;
constexpr int kHW  = kH * kW;        // 262144
constexpr int kHW4 = kHW / 4;        // 65536 = 2^16
constexpr int kNVEC = kB * kHW4;     // 2097152 float4-groups of pixels
constexpr long long kNPIX = (long long)kB * kHW;  // 8388608

// acc layout in d_ws (13 floats):
// [0] = ce_sum
// [1..4]  = prob_sum[c]
// [5..8]  = intersection[c]
// [9..12] = count[c]

__global__ __launch_bounds__(256) void loss_main(const float* __restrict__ logits,
                                                 const int* __restrict__ tgt,
                                                 float* __restrict__ acc) {
    int tid = blockIdx.x * blockDim.x + threadIdx.x;
    int stride = gridDim.x * blockDim.x;

    float ce = 0.f;
    float ps0 = 0.f, ps1 = 0.f, ps2 = 0.f, ps3 = 0.f;
    float it0 = 0.f, it1 = 0.f, it2 = 0.f, it3 = 0.f;
    float ct0 = 0.f, ct1 = 0.f, ct2 = 0.f, ct3 = 0.f;

    const float4* lg4 = reinterpret_cast<const float4*>(logits);
    const int4*   tg4 = reinterpret_cast<const int4*>(tgt);

    for (int v = tid; v < kNVEC; v += stride) {
        int b   = v >> 16;            // v / kHW4
        int hw4 = v & (kHW4 - 1);
        int base = b * (kC * kHW4) + hw4;   // float4-unit index
        float4 a0 = lg4[base];
        float4 a1 = lg4[base + kHW4];
        float4 a2 = lg4[base + 2 * kHW4];
        float4 a3 = lg4[base + 3 * kHW4];
        int4 t4 = tg4[b * kHW4 + hw4];

        auto px = [&](float x0, float x1, float x2, float x3, int t) {
            float m = fmaxf(fmaxf(x0, x1), fmaxf(x2, x3));
            float e0 = __expf(x0 - m);
            float e1 = __expf(x1 - m);
            float e2 = __expf(x2 - m);
            float e3 = __expf(x3 - m);
            float se = e0 + e1 + e2 + e3;
            float inv = 1.0f / se;
            float xt = (t == 0) ? x0 : (t == 1) ? x1 : (t == 2) ? x2 : x3;
            ce += __logf(se) + (m - xt);
            float p0 = e0 * inv, p1 = e1 * inv, p2 = e2 * inv, p3 = e3 * inv;
            ps0 += p0; ps1 += p1; ps2 += p2; ps3 += p3;
            bool b0 = (t == 0), b1 = (t == 1), b2 = (t == 2), b3 = (t == 3);
            it0 += b0 ? p0 : 0.f;  it1 += b1 ? p1 : 0.f;
            it2 += b2 ? p2 : 0.f;  it3 += b3 ? p3 : 0.f;
            ct0 += b0 ? 1.f : 0.f; ct1 += b1 ? 1.f : 0.f;
            ct2 += b2 ? 1.f : 0.f; ct3 += b3 ? 1.f : 0.f;
        };
        px(a0.x, a1.x, a2.x, a3.x, t4.x);
        px(a0.y, a1.y, a2.y, a3.y, t4.y);
        px(a0.z, a1.z, a2.z, a3.z, t4.z);
        px(a0.w, a1.w, a2.w, a3.w, t4.w);
    }

    // Block-level reduction of the 13 partials.
    float vals[13] = {ce, ps0, ps1, ps2, ps3, it0, it1, it2, it3, ct0, ct1, ct2, ct3};
    #pragma unroll
    for (int i = 0; i < 13; ++i) {
        float v = vals[i];
        #pragma unroll
        for (int off = 32; off > 0; off >>= 1) v += __shfl_down(v, off);
        vals[i] = v;
    }
    __shared__ float smem[4][13];
    int lane = threadIdx.x & 63;
    int wave = threadIdx.x >> 6;
    if (lane == 0) {
        #pragma unroll
        for (int i = 0; i < 13; ++i) smem[wave][i] = vals[i];
    }
    __syncthreads();
    if (threadIdx.x < 13) {
        float s = smem[0][threadIdx.x] + smem[1][threadIdx.x] +
                  smem[2][threadIdx.x] + smem[3][threadIdx.x];
        atomicAdd(&acc[threadIdx.x], s);
    }
}

__global__ void finalize_kernel(const float* __restrict__ acc, float* __restrict__ out) {
    if (threadIdx.x == 0 && blockIdx.x == 0) {
        float ce = acc[0] / (float)kNPIX;
        float dsum = 0.f;
        #pragma unroll
        for (int c = 0; c < 4; ++c) {
            float I = acc[5 + c];
            float U = acc[1 + c] + acc[9 + c];
            dsum += 1.f - (2.f * I + SMOOTH) / (U + SMOOTH);
        }
        float dice = dsum * 0.25f;
        out[0] = ALPHA * ce + BETA * dice;
        out[1] = 1.f - dice;
    }
}

extern "C" void kernel_launch(void* const* d_in, const int* in_sizes, int n_in,
                              void* d_out, int out_size, void* d_ws, size_t ws_size,
                              hipStream_t stream) {
    const float* logits = (const float*)d_in[0];
    const int*   tgt    = (const int*)d_in[1];
    float* out = (float*)d_out;
    float* acc = (float*)d_ws;

    hipMemsetAsync(acc, 0, 13 * sizeof(float), stream);

    const int threads = 256;
    const int blocks = 2048;   // grid-stride: 4 float4-groups per thread
    loss_main<<<blocks, threads, 0, stream>>>(logits, tgt, acc);
    finalize_kernel<<<1, 64, 0, stream>>>(acc, out);
}